// Round 11
// baseline (198.161 us; speedup 1.0000x reference)
//
#include <hip/hip_runtime.h>
#include <hip/hip_bf16.h>

typedef __attribute__((ext_vector_type(8))) _Float16 f16x8;  // 8 fp16 (4 VGPR)
typedef __attribute__((ext_vector_type(4))) float f32x4;     // MFMA C/D frag

constexpr int Sc  = 2048;
constexpr int Dc  = 1024;
constexpr int Hc  = 16;
constexpr int HDc = 64;
constexpr int Mc  = 4096;  // B*S

constexpr float ECs = 0.18033688011112042f;  // log2(e)/8, folded into Q

__device__ __forceinline__ ushort f2h(float f) {
  return __builtin_bit_cast(ushort, (_Float16)f);
}

// async global->LDS, 16B per lane; LDS dest = wave-uniform base + lane*16
__device__ __forceinline__ void glds16(const ushort* g, ushort* l) {
  __builtin_amdgcn_global_load_lds(
      (const __attribute__((address_space(1))) unsigned int*)(g),
      (__attribute__((address_space(3))) unsigned int*)(l), 16, 0, 0);
}

union US8 {
  ushort u[8];
  uint   w[4];
  f16x8  v;
};

// ---------------------------------------------------------------------------
// prep: merged split_x (blocks 0..4095) + split_wt (blocks 4096..5119).
// ---------------------------------------------------------------------------
struct SplitP {
  const float* W[4];
  ushort*      Th[4];
};

__global__ __launch_bounds__(256) void prep_kernel(
    const float* __restrict__ X, ushort* __restrict__ Xh, SplitP p) {
  __shared__ float T[64][69];
  const int wid = blockIdx.x;
  const int t   = threadIdx.x;
  if (wid < 4096) {
    const int i    = wid * 256 + t;
    const float4 v = ((const float4*)X)[i];
    ushort4 h;
    h.x = f2h(v.x);
    h.y = f2h(v.y);
    h.z = f2h(v.z);
    h.w = f2h(v.w);
    ((ushort4*)Xh)[i] = h;
    return;
  }
  const int w2 = wid - 4096;
  const int z  = w2 >> 8;
  const int by = (w2 >> 4) & 15;
  const int bx = w2 & 15;
  const float* W = p.W[z];
  const int c  = (t & 15) * 4;
  const int r  = t >> 4;
  const int n0 = bx * 64, k0 = by * 64;
#pragma unroll
  for (int pp = 0; pp < 4; ++pp) {
    const int k    = r + pp * 16;
    const float4 v = *(const float4*)(W + (size_t)(k0 + k) * 1024 + n0 + c);
    T[k][c + 0] = v.x;
    T[k][c + 1] = v.y;
    T[k][c + 2] = v.z;
    T[k][c + 3] = v.w;
  }
  __syncthreads();
#pragma unroll
  for (int pp = 0; pp < 4; ++pp) {
    const int n = r + pp * 16;
    ushort4 h;
    h.x = f2h(T[c + 0][n]);
    h.y = f2h(T[c + 1][n]);
    h.z = f2h(T[c + 2][n]);
    h.w = f2h(T[c + 3][n]);
    *(ushort4*)(p.Th[z] + (size_t)(n0 + n) * 1024 + k0 + c) = h;
  }
}

// ---------------------------------------------------------------------------
// fp16 MFMA GEMM, BK=64, global_load_lds staging (m97 pattern, T-catalog):
// replaces 16 b128 global->VGPR loads + 8 ds_writes per thread/k-tile with
// 8 global_load_lds dwordx4 (no VGPR round-trip; m151: 874 vs 646 TF).
// gload_lds writes linearly (base + lane*16B), so the chunk swizzle moves to
// the SOURCE address (rule #21): lane l of wave w stages row am=16w+(l>>2),
// logical chunk q=((l&3)-(am>>1))&3 -> each chunk lands at the physical slot
// the (unchanged) fragment-read swizzle expects. LDS image and accumulation
// order bit-identical to r10.
// ---------------------------------------------------------------------------
struct GemmP {
  const ushort* Bh[3];
  const float*  bias[3];
  void*         Out[3];
};

template <bool QKV>
__global__ __launch_bounds__(256) void gemm_f16(
    const ushort* __restrict__ A, GemmP p) {
  __shared__ __align__(16) ushort As[2][128 * 32];
  __shared__ __align__(16) ushort Bs[2][128 * 32];

  const int t  = threadIdx.x;
  const int z  = blockIdx.z;
  const int m0 = blockIdx.x * 128, n0 = blockIdx.y * 128;
  const ushort* Bh  = p.Bh[z];
  const float* bias = p.bias[z];

  const int lane = t & 63, wave = t >> 6;
  const int wm = (wave & 1) * 64, wn = (wave >> 1) * 64;

  f32x4 acc[4][4];
#pragma unroll
  for (int i = 0; i < 4; ++i)
#pragma unroll
    for (int j = 0; j < 4; ++j) acc[i][j] = (f32x4){0.f, 0.f, 0.f, 0.f};

  // gload_lds staging geometry: wave w covers LDS rows [16w,16w+16) (seg0)
  // and [64+16w, 64+16w+16) (seg1) of each sub-tile; 1 KB per call.
  // lane l -> row am = 16w + (l>>2), physical slot s = l&3, logical chunk
  // q = (s - (am>>1)) & 3  (identical for am and am+64 since 32 % 4 == 0).
  const int am = wave * 16 + (lane >> 2);
  const int q  = ((lane & 3) - (am >> 1)) & 3;
  const ushort* gA = A  + (size_t)(m0 + am) * 1024 + q * 8;
  const ushort* gB = Bh + (size_t)(n0 + am) * 1024 + q * 8;
  const int ls0 = wave * 512;         // seg0 elem base (rows 16w..16w+15)
  const int ls1 = 2048 + wave * 512;  // seg1 elem base (rows 64+16w..)

  // fragment reads: row = wm/wn + i*16 + fr; physical slot of logical chunk
  // (lane>>4) there is ((lane>>4)+(fr>>1))&3 (wm/2, i*8 ≡ 0 mod 4).
  const int fr  = lane & 15;
  const int fkb = (((lane >> 4) + (fr >> 1)) & 3) * 16;

  for (int k0 = 0; k0 < 1024; k0 += 64) {
    __syncthreads();  // all waves done reading previous tile
    glds16(gA + k0,                  &As[0][ls0]);
    glds16(gA + k0 + 64 * 1024,      &As[0][ls1]);
    glds16(gA + k0 + 32,             &As[1][ls0]);
    glds16(gA + k0 + 32 + 64 * 1024, &As[1][ls1]);
    glds16(gB + k0,                  &Bs[0][ls0]);
    glds16(gB + k0 + 64 * 1024,      &Bs[0][ls1]);
    glds16(gB + k0 + 32,             &Bs[1][ls0]);
    glds16(gB + k0 + 32 + 64 * 1024, &Bs[1][ls1]);
    __syncthreads();  // drains vmcnt(0): staged data visible to all waves

#pragma unroll
    for (int kk = 0; kk < 2; ++kk) {
      f16x8 a[4], b_h[4];
#pragma unroll
      for (int i = 0; i < 4; ++i) {
        const int ra = (wm + i * 16 + fr) * 64 + fkb;  // bytes within sub-tile
        const int rb = (wn + i * 16 + fr) * 64 + fkb;
        a[i]   = *(const f16x8*)((const char*)As[kk] + ra);
        b_h[i] = *(const f16x8*)((const char*)Bs[kk] + rb);
      }
#pragma unroll
      for (int i = 0; i < 4; ++i)
#pragma unroll
        for (int j = 0; j < 4; ++j)
          acc[i][j] = __builtin_amdgcn_mfma_f32_16x16x32_f16(a[i], b_h[j], acc[i][j], 0, 0, 0);
    }
  }

  const float osc = (QKV && z == 0) ? ECs : 1.0f;
  const int cr = (lane >> 4) * 4;
  const int cc = lane & 15;
#pragma unroll
  for (int j = 0; j < 4; ++j) {
    const int n    = n0 + wn + j * 16 + cc;
    const float bv = bias[n];
#pragma unroll
    for (int i = 0; i < 4; ++i) {
      const int mb = m0 + wm + i * 16 + cr;
#pragma unroll
      for (int r = 0; r < 4; ++r) {
        const int m   = mb + r;
        const float v = (acc[i][j][r] + bv) * osc;
        if (QKV) {
          const int b = m >> 11, s = m & 2047, h = n >> 6, hd = n & 63;
          ((ushort*)p.Out[z])[(((size_t)(b * Hc + h) * Sc + s) << 6) + hd] = f2h(v);
        } else {
          ((float*)p.Out[z])[(size_t)m * 1024 + n] = v;
        }
      }
    }
  }
}

// ---------------------------------------------------------------------------
// MFMA flash attention — r7/r10 structure verbatim (measured 52.8 us, best of
// 7 structural variants). QBLOCK=256: each wave serves 64 q-rows as two
// sequential 32-row halves; 256 blocks, bh=wg&31 (XCD L2 affinity);
// single-buffer 2-barrier staging; setprio around MFMA clusters; hoisted
// zero-C QK init. ~662 TF effective = 77% of the GEMM-structure rate.
// ---------------------------------------------------------------------------
__global__ __launch_bounds__(256, 2) void attn_mfma3(
    const ushort* __restrict__ Q, const ushort* __restrict__ K,
    const ushort* __restrict__ V, ushort* __restrict__ CTX) {
  __shared__ __align__(16) ushort Ks[64 * 64];
  __shared__ __align__(16) ushort Vt[64 * 64];  // [d][l(k) swizzled]

  const int t    = threadIdx.x;
  const int lane = t & 63, wave = t >> 6;
  const int c16 = lane & 15, quad = lane >> 4;
  const int wg = blockIdx.x;
  const int bh = wg & 31, qt = wg >> 5;  // bh fast: xcd = bh%8 (L2 affinity)
  const int bb = bh >> 4, hh = bh & 15;

  const ushort* Qb = Q + (size_t)bh * Sc * HDc + (size_t)qt * 256 * HDc;
  const ushort* Kb = K + (size_t)bh * Sc * HDc;
  const ushort* Vb = V + (size_t)bh * Sc * HDc;

  // 64 q-rows per wave: [qh][mt][c]
  f16x8 aq[2][2][2];
#pragma unroll
  for (int qh = 0; qh < 2; ++qh)
#pragma unroll
    for (int mt = 0; mt < 2; ++mt)
#pragma unroll
      for (int c = 0; c < 2; ++c)
        aq[qh][mt][c] = *(const f16x8*)(Qb +
            (size_t)(wave * 64 + qh * 32 + mt * 16 + c16) * 64 + c * 32 + quad * 8);

  US8 ones_u;
#pragma unroll
  for (int e = 0; e < 8; ++e) ones_u.u[e] = 0x3C00;  // fp16 1.0
  const f16x8 ones = ones_u.v;
  const f32x4 kZ = (f32x4){0.f, 0.f, 0.f, 0.f};  // hoisted MFMA C=0

  f32x4 ctx[2][2][4], lacc[2][2];
#pragma unroll
  for (int qh = 0; qh < 2; ++qh)
#pragma unroll
    for (int mt = 0; mt < 2; ++mt) {
      lacc[qh][mt] = (f32x4){0.f, 0.f, 0.f, 0.f};
#pragma unroll
      for (int j = 0; j < 4; ++j) ctx[qh][mt][j] = (f32x4){0.f, 0.f, 0.f, 0.f};
    }

  const int fslot = ((quad + (c16 >> 1)) & 3) * 8;

  const int krow = t >> 2, kac = t & 3;
  const int kl = krow * 64 + ((kac + (krow >> 1)) & 3) * 8;

  const int kg = t & 15, dg = t >> 4;
  const int vc   = (kg >> 3) * 32;
  const int vq   = kg & 3;
  const int vsub = ((kg >> 2) & 1) * 4;

  const ushort* gK = Kb + (size_t)krow * 64 + kac * 8;
  const ushort* gV = Vb + (size_t)(kg * 4) * 64 + dg * 4;

  f16x8 kr0, kr1;
  ushort4 vr[4];
  kr0 = *(const f16x8*)(gK);
  kr1 = *(const f16x8*)(gK + 32);
#pragma unroll
  for (int i = 0; i < 4; ++i) vr[i] = *(const ushort4*)(gV + (size_t)i * 64);

  for (int kt = 0; kt < 32; ++kt) {
    __syncthreads();
    *(f16x8*)&Ks[kl]      = kr0;
    *(f16x8*)&Ks[kl + 32] = kr1;
    {
      const uint* w0 = (const uint*)&vr[0];
      const uint* w1 = (const uint*)&vr[1];
      const uint* w2 = (const uint*)&vr[2];
      const uint* w3 = (const uint*)&vr[3];
#pragma unroll
      for (int j = 0; j < 4; ++j) {
        const int  wd  = j >> 1;
        const uint sel = (j & 1) ? 0x07060302u : 0x05040100u;
        const uint lo  = __builtin_amdgcn_perm(w1[wd], w0[wd], sel);
        const uint hi  = __builtin_amdgcn_perm(w3[wd], w2[wd], sel);
        const int row  = dg * 4 + j;
        const int slot = (vq + (row >> 1)) & 3;
        *(uint2*)&Vt[row * 64 + vc + slot * 8 + vsub] = make_uint2(lo, hi);
      }
    }
    __syncthreads();

    if (kt < 31) {
      const size_t adv = (size_t)(kt + 1) * 64 * 64;
      kr0 = *(const f16x8*)(gK + adv);
      kr1 = *(const f16x8*)(gK + adv + 32);
#pragma unroll
      for (int i = 0; i < 4; ++i) vr[i] = *(const ushort4*)(gV + adv + (size_t)i * 64);
    }

#pragma unroll
    for (int qh = 0; qh < 2; ++qh) {
      // QK^T for this q-half (c=0 with hoisted zero C)
      f32x4 st[2][4];
      __builtin_amdgcn_s_setprio(1);
#pragma unroll
      for (int j = 0; j < 4; ++j) {
        const f16x8 ak0 = *(const f16x8*)&Ks[(j * 16 + c16) * 64 + fslot];
        st[0][j] = __builtin_amdgcn_mfma_f32_16x16x32_f16(ak0, aq[qh][0][0], kZ, 0, 0, 0);
        st[1][j] = __builtin_amdgcn_mfma_f32_16x16x32_f16(ak0, aq[qh][1][0], kZ, 0, 0, 0);
      }
#pragma unroll
      for (int j = 0; j < 4; ++j) {
        const f16x8 ak1 = *(const f16x8*)&Ks[(j * 16 + c16) * 64 + 32 + fslot];
        st[0][j] = __builtin_amdgcn_mfma_f32_16x16x32_f16(ak1, aq[qh][0][1], st[0][j], 0, 0, 0);
        st[1][j] = __builtin_amdgcn_mfma_f32_16x16x32_f16(ak1, aq[qh][1][1], st[1][j], 0, 0, 0);
      }
      __builtin_amdgcn_s_setprio(0);

      US8 pf[2][2];
#pragma unroll
      for (int mt = 0; mt < 2; ++mt)
#pragma unroll
        for (int c2 = 0; c2 < 2; ++c2)
#pragma unroll
          for (int w = 0; w < 4; ++w) {
            const int jj = c2 * 2 + (w >> 1);
            const int r0 = (w & 1) * 2;
            const float pe = __builtin_amdgcn_exp2f(st[mt][jj][r0]);
            const float po = __builtin_amdgcn_exp2f(st[mt][jj][r0 + 1]);
            const auto pk = __builtin_amdgcn_cvt_pkrtz(pe, po);
            pf[mt][c2].w[w] = __builtin_bit_cast(uint, pk);
          }

      __builtin_amdgcn_s_setprio(1);
#pragma unroll
      for (int c2 = 0; c2 < 2; ++c2) {
        lacc[qh][0] = __builtin_amdgcn_mfma_f32_16x16x32_f16(pf[0][c2].v, ones, lacc[qh][0], 0, 0, 0);
        lacc[qh][1] = __builtin_amdgcn_mfma_f32_16x16x32_f16(pf[1][c2].v, ones, lacc[qh][1], 0, 0, 0);
#pragma unroll
        for (int j = 0; j < 4; ++j) {
          const f16x8 bv = *(const f16x8*)&Vt[(j * 16 + c16) * 64 + c2 * 32 + fslot];
          ctx[qh][0][j] = __builtin_amdgcn_mfma_f32_16x16x32_f16(pf[0][c2].v, bv, ctx[qh][0][j], 0, 0, 0);
          ctx[qh][1][j] = __builtin_amdgcn_mfma_f32_16x16x32_f16(pf[1][c2].v, bv, ctx[qh][1][j], 0, 0, 0);
        }
      }
      __builtin_amdgcn_s_setprio(0);
    }
  }

#pragma unroll
  for (int qh = 0; qh < 2; ++qh)
#pragma unroll
    for (int mt = 0; mt < 2; ++mt) {
#pragma unroll
      for (int r = 0; r < 4; ++r) {
        const float inv = 1.f / lacc[qh][mt][r];
        const int srow  = qt * 256 + wave * 64 + qh * 32 + mt * 16 + quad * 4 + r;
        const size_t rb = ((size_t)(bb * Sc + srow)) * 1024 + hh * 64;
#pragma unroll
        for (int j = 0; j < 4; ++j)
          CTX[rb + j * 16 + c16] = f2h(ctx[qh][mt][j][r] * inv);
      }
    }
}

extern "C" void kernel_launch(void* const* d_in, const int* in_sizes, int n_in,
                              void* d_out, int out_size, void* d_ws, size_t ws_size,
                              hipStream_t stream) {
  (void)in_sizes; (void)n_in; (void)out_size; (void)ws_size;
  const float* x  = (const float*)d_in[0];
  const float* Wq = (const float*)d_in[1];
  const float* bq = (const float*)d_in[2];
  const float* Wk = (const float*)d_in[3];
  const float* bk = (const float*)d_in[4];
  const float* Wv = (const float*)d_in[5];
  const float* bv = (const float*)d_in[6];
  const float* Wo = (const float*)d_in[7];
  const float* bo = (const float*)d_in[8];

  const size_t MB = 1024 * 1024;
  char* w    = (char*)d_ws;
  ushort* Qw  = (ushort*)(w + 0 * MB);   // [B,H,S,HD] fp16 (pre-scaled by EC)
  ushort* Kw  = (ushort*)(w + 8 * MB);
  ushort* Vw  = (ushort*)(w + 16 * MB);
  ushort* Cw  = (ushort*)(w + 24 * MB);  // ctx [M,1024] fp16
  ushort* Xh  = (ushort*)(w + 32 * MB);  // x fp16 [M,1024]
  ushort* WT  = (ushort*)(w + 40 * MB);  // 4 x 2 MB fp16 W^T planes
  ushort* Whq = WT + 0 * 1048576;
  ushort* Whk = WT + 1 * 1048576;
  ushort* Whv = WT + 2 * 1048576;
  ushort* Who = WT + 3 * 1048576;

  const dim3 blk(256);

  SplitP sp;
  sp.W[0] = Wq; sp.W[1] = Wk; sp.W[2] = Wv; sp.W[3] = Wo;
  sp.Th[0] = Whq; sp.Th[1] = Whk; sp.Th[2] = Whv; sp.Th[3] = Who;
  prep_kernel<<<dim3(5120), blk, 0, stream>>>(x, Xh, sp);

  GemmP pq;
  pq.Bh[0] = Whq; pq.Bh[1] = Whk; pq.Bh[2] = Whv;
  pq.bias[0] = bq; pq.bias[1] = bk; pq.bias[2] = bv;
  pq.Out[0] = Qw; pq.Out[1] = Kw; pq.Out[2] = Vw;
  gemm_f16<true><<<dim3(Mc / 128, Dc / 128, 3), blk, 0, stream>>>(Xh, pq);

  attn_mfma3<<<dim3(256), blk, 0, stream>>>(Qw, Kw, Vw, Cw);

  GemmP po;
  po.Bh[0] = po.Bh[1] = po.Bh[2] = Who;
  po.bias[0] = po.bias[1] = po.bias[2] = bo;
  po.Out[0] = po.Out[1] = po.Out[2] = d_out;
  gemm_f16<false><<<dim3(Mc / 128, Dc / 128, 1), blk, 0, stream>>>(Cw, po);
}

// Round 12
// 184.424 us; speedup vs baseline: 1.0745x; 1.0745x over previous
//
#include <hip/hip_runtime.h>
#include <hip/hip_bf16.h>

typedef __attribute__((ext_vector_type(8))) _Float16 f16x8;  // 8 fp16 (4 VGPR)
typedef __attribute__((ext_vector_type(4))) float f32x4;     // MFMA C/D frag

constexpr int Sc  = 2048;
constexpr int Dc  = 1024;
constexpr int Hc  = 16;
constexpr int HDc = 64;
constexpr int Mc  = 4096;  // B*S

constexpr float ECs = 0.18033688011112042f;  // log2(e)/8, folded into Q

__device__ __forceinline__ ushort f2h(float f) {
  return __builtin_bit_cast(ushort, (_Float16)f);
}

// async global->LDS, 16B per lane; LDS dest = wave-uniform base + lane*16
__device__ __forceinline__ void glds16(const ushort* g, ushort* l) {
  __builtin_amdgcn_global_load_lds(
      (const __attribute__((address_space(1))) unsigned int*)(g),
      (__attribute__((address_space(3))) unsigned int*)(l), 16, 0, 0);
}

union US8 {
  ushort u[8];
  uint   w[4];
  f16x8  v;
};

// ---------------------------------------------------------------------------
// prep: merged split_x (blocks 0..4095) + split_wt (blocks 4096..5119).
// ---------------------------------------------------------------------------
struct SplitP {
  const float* W[4];
  ushort*      Th[4];
};

__global__ __launch_bounds__(256) void prep_kernel(
    const float* __restrict__ X, ushort* __restrict__ Xh, SplitP p) {
  __shared__ float T[64][69];
  const int wid = blockIdx.x;
  const int t   = threadIdx.x;
  if (wid < 4096) {
    const int i    = wid * 256 + t;
    const float4 v = ((const float4*)X)[i];
    ushort4 h;
    h.x = f2h(v.x);
    h.y = f2h(v.y);
    h.z = f2h(v.z);
    h.w = f2h(v.w);
    ((ushort4*)Xh)[i] = h;
    return;
  }
  const int w2 = wid - 4096;
  const int z  = w2 >> 8;
  const int by = (w2 >> 4) & 15;
  const int bx = w2 & 15;
  const float* W = p.W[z];
  const int c  = (t & 15) * 4;
  const int r  = t >> 4;
  const int n0 = bx * 64, k0 = by * 64;
#pragma unroll
  for (int pp = 0; pp < 4; ++pp) {
    const int k    = r + pp * 16;
    const float4 v = *(const float4*)(W + (size_t)(k0 + k) * 1024 + n0 + c);
    T[k][c + 0] = v.x;
    T[k][c + 1] = v.y;
    T[k][c + 2] = v.z;
    T[k][c + 3] = v.w;
  }
  __syncthreads();
#pragma unroll
  for (int pp = 0; pp < 4; ++pp) {
    const int n = r + pp * 16;
    ushort4 h;
    h.x = f2h(T[c + 0][n]);
    h.y = f2h(T[c + 1][n]);
    h.z = f2h(T[c + 2][n]);
    h.w = f2h(T[c + 3][n]);
    *(ushort4*)(p.Th[z] + (size_t)(n0 + n) * 1024 + k0 + c) = h;
  }
}

// ---------------------------------------------------------------------------
// fp16 MFMA GEMM — glds16 + double-buffered single-barrier pipeline (the
// ACTUAL m97/m151 schedule; r11's version issued loads then drained with no
// overlap and regressed). Per k-step: {barrier; issue 4x glds16 (tile k+1 ->
// buf p^1); ds_read+16 MFMA from buf p}. The next barrier's implicit
// vmcnt(0) drain lands after a full compute phase -> loads hide under MFMA.
// No ds_writes, no staging VGPRs (m151: glds 874 vs reg-staged 646 TF).
// LDS 2x(8+8) KB = 32 KB (same as r10). Source-swizzled addresses (rule #21)
// reproduce r10's LDS image exactly; accumulation order bit-identical.
// ---------------------------------------------------------------------------
struct GemmP {
  const ushort* Bh[3];
  const float*  bias[3];
  void*         Out[3];
};

template <bool QKV>
__global__ __launch_bounds__(256) void gemm_f16(
    const ushort* __restrict__ A, GemmP p) {
  __shared__ __align__(16) ushort As[2][128 * 32];
  __shared__ __align__(16) ushort Bs[2][128 * 32];

  const int t  = threadIdx.x;
  const int z  = blockIdx.z;
  const int m0 = blockIdx.x * 128, n0 = blockIdx.y * 128;
  const ushort* Bh  = p.Bh[z];
  const float* bias = p.bias[z];

  const int lane = t & 63, wave = t >> 6;
  const int wm = (wave & 1) * 64, wn = (wave >> 1) * 64;

  f32x4 acc[4][4];
#pragma unroll
  for (int i = 0; i < 4; ++i)
#pragma unroll
    for (int j = 0; j < 4; ++j) acc[i][j] = (f32x4){0.f, 0.f, 0.f, 0.f};

  // glds staging geometry: wave w covers LDS rows [16w,16w+16) (seg0) and
  // [64+16w, 64+16w+16) (seg1); 1 KB per call. lane l -> row am=16w+(l>>2),
  // physical slot s=l&3, logical chunk q=(s-(am>>1))&3 (same for am, am+64).
  const int am = wave * 16 + (lane >> 2);
  const int q  = ((lane & 3) - (am >> 1)) & 3;
  const ushort* gA = A  + (size_t)(m0 + am) * 1024 + q * 8;
  const ushort* gB = Bh + (size_t)(n0 + am) * 1024 + q * 8;
  const int ls0 = wave * 512;         // seg0 elem base (rows 16w..16w+15)
  const int ls1 = 2048 + wave * 512;  // seg1 elem base (rows 64+16w..)

  // fragment reads: row = wm/wn + i*16 + fr; physical slot of logical chunk
  // (lane>>4) there is ((lane>>4)+(fr>>1))&3 (wm/2, i*8 ≡ 0 mod 4).
  const int fr  = lane & 15;
  const int fkb = (((lane >> 4) + (fr >> 1)) & 3) * 16;

  // prologue: tile 0 -> buf 0
  glds16(gA,             &As[0][ls0]);
  glds16(gA + 64 * 1024, &As[0][ls1]);
  glds16(gB,             &Bs[0][ls0]);
  glds16(gB + 64 * 1024, &Bs[0][ls1]);

  int bp = 0;
  for (int k0 = 0; k0 < 1024; k0 += 32) {
    __syncthreads();  // drains own vmcnt -> buf[bp] staged; buf[bp^1] reads done
    if (k0 + 32 < 1024) {  // issue next tile早 -> overlaps the compute below
      glds16(gA + k0 + 32,             &As[bp ^ 1][ls0]);
      glds16(gA + k0 + 32 + 64 * 1024, &As[bp ^ 1][ls1]);
      glds16(gB + k0 + 32,             &Bs[bp ^ 1][ls0]);
      glds16(gB + k0 + 32 + 64 * 1024, &Bs[bp ^ 1][ls1]);
    }

    f16x8 a[4], b_h[4];
#pragma unroll
    for (int i = 0; i < 4; ++i) {
      const int ra = (wm + i * 16 + fr) * 64 + fkb;  // bytes within tile
      const int rb = (wn + i * 16 + fr) * 64 + fkb;
      a[i]   = *(const f16x8*)((const char*)As[bp] + ra);
      b_h[i] = *(const f16x8*)((const char*)Bs[bp] + rb);
    }
#pragma unroll
    for (int i = 0; i < 4; ++i)
#pragma unroll
      for (int j = 0; j < 4; ++j)
        acc[i][j] = __builtin_amdgcn_mfma_f32_16x16x32_f16(a[i], b_h[j], acc[i][j], 0, 0, 0);
    bp ^= 1;
  }

  const float osc = (QKV && z == 0) ? ECs : 1.0f;
  const int cr = (lane >> 4) * 4;
  const int cc = lane & 15;
#pragma unroll
  for (int j = 0; j < 4; ++j) {
    const int n    = n0 + wn + j * 16 + cc;
    const float bv = bias[n];
#pragma unroll
    for (int i = 0; i < 4; ++i) {
      const int mb = m0 + wm + i * 16 + cr;
#pragma unroll
      for (int r = 0; r < 4; ++r) {
        const int m   = mb + r;
        const float v = (acc[i][j][r] + bv) * osc;
        if (QKV) {
          const int b = m >> 11, s = m & 2047, h = n >> 6, hd = n & 63;
          ((ushort*)p.Out[z])[(((size_t)(b * Hc + h) * Sc + s) << 6) + hd] = f2h(v);
        } else {
          ((float*)p.Out[z])[(size_t)m * 1024 + n] = v;
        }
      }
    }
  }
}

// ---------------------------------------------------------------------------
// MFMA flash attention — r7/r10 structure verbatim (measured 52.8 us, best of
// 7 structural variants). QBLOCK=256: each wave serves 64 q-rows as two
// sequential 32-row halves; 256 blocks, bh=wg&31 (XCD L2 affinity);
// single-buffer 2-barrier staging; setprio around MFMA clusters; hoisted
// zero-C QK init. ~662 TF effective = 77% of the GEMM-structure rate.
// ---------------------------------------------------------------------------
__global__ __launch_bounds__(256, 2) void attn_mfma3(
    const ushort* __restrict__ Q, const ushort* __restrict__ K,
    const ushort* __restrict__ V, ushort* __restrict__ CTX) {
  __shared__ __align__(16) ushort Ks[64 * 64];
  __shared__ __align__(16) ushort Vt[64 * 64];  // [d][l(k) swizzled]

  const int t    = threadIdx.x;
  const int lane = t & 63, wave = t >> 6;
  const int c16 = lane & 15, quad = lane >> 4;
  const int wg = blockIdx.x;
  const int bh = wg & 31, qt = wg >> 5;  // bh fast: xcd = bh%8 (L2 affinity)
  const int bb = bh >> 4, hh = bh & 15;

  const ushort* Qb = Q + (size_t)bh * Sc * HDc + (size_t)qt * 256 * HDc;
  const ushort* Kb = K + (size_t)bh * Sc * HDc;
  const ushort* Vb = V + (size_t)bh * Sc * HDc;

  // 64 q-rows per wave: [qh][mt][c]
  f16x8 aq[2][2][2];
#pragma unroll
  for (int qh = 0; qh < 2; ++qh)
#pragma unroll
    for (int mt = 0; mt < 2; ++mt)
#pragma unroll
      for (int c = 0; c < 2; ++c)
        aq[qh][mt][c] = *(const f16x8*)(Qb +
            (size_t)(wave * 64 + qh * 32 + mt * 16 + c16) * 64 + c * 32 + quad * 8);

  US8 ones_u;
#pragma unroll
  for (int e = 0; e < 8; ++e) ones_u.u[e] = 0x3C00;  // fp16 1.0
  const f16x8 ones = ones_u.v;
  const f32x4 kZ = (f32x4){0.f, 0.f, 0.f, 0.f};  // hoisted MFMA C=0

  f32x4 ctx[2][2][4], lacc[2][2];
#pragma unroll
  for (int qh = 0; qh < 2; ++qh)
#pragma unroll
    for (int mt = 0; mt < 2; ++mt) {
      lacc[qh][mt] = (f32x4){0.f, 0.f, 0.f, 0.f};
#pragma unroll
      for (int j = 0; j < 4; ++j) ctx[qh][mt][j] = (f32x4){0.f, 0.f, 0.f, 0.f};
    }

  const int fslot = ((quad + (c16 >> 1)) & 3) * 8;

  const int krow = t >> 2, kac = t & 3;
  const int kl = krow * 64 + ((kac + (krow >> 1)) & 3) * 8;

  const int kg = t & 15, dg = t >> 4;
  const int vc   = (kg >> 3) * 32;
  const int vq   = kg & 3;
  const int vsub = ((kg >> 2) & 1) * 4;

  const ushort* gK = Kb + (size_t)krow * 64 + kac * 8;
  const ushort* gV = Vb + (size_t)(kg * 4) * 64 + dg * 4;

  f16x8 kr0, kr1;
  ushort4 vr[4];
  kr0 = *(const f16x8*)(gK);
  kr1 = *(const f16x8*)(gK + 32);
#pragma unroll
  for (int i = 0; i < 4; ++i) vr[i] = *(const ushort4*)(gV + (size_t)i * 64);

  for (int kt = 0; kt < 32; ++kt) {
    __syncthreads();
    *(f16x8*)&Ks[kl]      = kr0;
    *(f16x8*)&Ks[kl + 32] = kr1;
    {
      const uint* w0 = (const uint*)&vr[0];
      const uint* w1 = (const uint*)&vr[1];
      const uint* w2 = (const uint*)&vr[2];
      const uint* w3 = (const uint*)&vr[3];
#pragma unroll
      for (int j = 0; j < 4; ++j) {
        const int  wd  = j >> 1;
        const uint sel = (j & 1) ? 0x07060302u : 0x05040100u;
        const uint lo  = __builtin_amdgcn_perm(w1[wd], w0[wd], sel);
        const uint hi  = __builtin_amdgcn_perm(w3[wd], w2[wd], sel);
        const int row  = dg * 4 + j;
        const int slot = (vq + (row >> 1)) & 3;
        *(uint2*)&Vt[row * 64 + vc + slot * 8 + vsub] = make_uint2(lo, hi);
      }
    }
    __syncthreads();

    if (kt < 31) {
      const size_t adv = (size_t)(kt + 1) * 64 * 64;
      kr0 = *(const f16x8*)(gK + adv);
      kr1 = *(const f16x8*)(gK + adv + 32);
#pragma unroll
      for (int i = 0; i < 4; ++i) vr[i] = *(const ushort4*)(gV + adv + (size_t)i * 64);
    }

#pragma unroll
    for (int qh = 0; qh < 2; ++qh) {
      // QK^T for this q-half (c=0 with hoisted zero C)
      f32x4 st[2][4];
      __builtin_amdgcn_s_setprio(1);
#pragma unroll
      for (int j = 0; j < 4; ++j) {
        const f16x8 ak0 = *(const f16x8*)&Ks[(j * 16 + c16) * 64 + fslot];
        st[0][j] = __builtin_amdgcn_mfma_f32_16x16x32_f16(ak0, aq[qh][0][0], kZ, 0, 0, 0);
        st[1][j] = __builtin_amdgcn_mfma_f32_16x16x32_f16(ak0, aq[qh][1][0], kZ, 0, 0, 0);
      }
#pragma unroll
      for (int j = 0; j < 4; ++j) {
        const f16x8 ak1 = *(const f16x8*)&Ks[(j * 16 + c16) * 64 + 32 + fslot];
        st[0][j] = __builtin_amdgcn_mfma_f32_16x16x32_f16(ak1, aq[qh][0][1], st[0][j], 0, 0, 0);
        st[1][j] = __builtin_amdgcn_mfma_f32_16x16x32_f16(ak1, aq[qh][1][1], st[1][j], 0, 0, 0);
      }
      __builtin_amdgcn_s_setprio(0);

      US8 pf[2][2];
#pragma unroll
      for (int mt = 0; mt < 2; ++mt)
#pragma unroll
        for (int c2 = 0; c2 < 2; ++c2)
#pragma unroll
          for (int w = 0; w < 4; ++w) {
            const int jj = c2 * 2 + (w >> 1);
            const int r0 = (w & 1) * 2;
            const float pe = __builtin_amdgcn_exp2f(st[mt][jj][r0]);
            const float po = __builtin_amdgcn_exp2f(st[mt][jj][r0 + 1]);
            const auto pk = __builtin_amdgcn_cvt_pkrtz(pe, po);
            pf[mt][c2].w[w] = __builtin_bit_cast(uint, pk);
          }

      __builtin_amdgcn_s_setprio(1);
#pragma unroll
      for (int c2 = 0; c2 < 2; ++c2) {
        lacc[qh][0] = __builtin_amdgcn_mfma_f32_16x16x32_f16(pf[0][c2].v, ones, lacc[qh][0], 0, 0, 0);
        lacc[qh][1] = __builtin_amdgcn_mfma_f32_16x16x32_f16(pf[1][c2].v, ones, lacc[qh][1], 0, 0, 0);
#pragma unroll
        for (int j = 0; j < 4; ++j) {
          const f16x8 bv = *(const f16x8*)&Vt[(j * 16 + c16) * 64 + c2 * 32 + fslot];
          ctx[qh][0][j] = __builtin_amdgcn_mfma_f32_16x16x32_f16(pf[0][c2].v, bv, ctx[qh][0][j], 0, 0, 0);
          ctx[qh][1][j] = __builtin_amdgcn_mfma_f32_16x16x32_f16(pf[1][c2].v, bv, ctx[qh][1][j], 0, 0, 0);
        }
      }
      __builtin_amdgcn_s_setprio(0);
    }
  }

#pragma unroll
  for (int qh = 0; qh < 2; ++qh)
#pragma unroll
    for (int mt = 0; mt < 2; ++mt) {
#pragma unroll
      for (int r = 0; r < 4; ++r) {
        const float inv = 1.f / lacc[qh][mt][r];
        const int srow  = qt * 256 + wave * 64 + qh * 32 + mt * 16 + quad * 4 + r;
        const size_t rb = ((size_t)(bb * Sc + srow)) * 1024 + hh * 64;
#pragma unroll
        for (int j = 0; j < 4; ++j)
          CTX[rb + j * 16 + c16] = f2h(ctx[qh][mt][j][r] * inv);
      }
    }
}

extern "C" void kernel_launch(void* const* d_in, const int* in_sizes, int n_in,
                              void* d_out, int out_size, void* d_ws, size_t ws_size,
                              hipStream_t stream) {
  (void)in_sizes; (void)n_in; (void)out_size; (void)ws_size;
  const float* x  = (const float*)d_in[0];
  const float* Wq = (const float*)d_in[1];
  const float* bq = (const float*)d_in[2];
  const float* Wk = (const float*)d_in[3];
  const float* bk = (const float*)d_in[4];
  const float* Wv = (const float*)d_in[5];
  const float* bv = (const float*)d_in[6];
  const float* Wo = (const float*)d_in[7];
  const float* bo = (const float*)d_in[8];

  const size_t MB = 1024 * 1024;
  char* w    = (char*)d_ws;
  ushort* Qw  = (ushort*)(w + 0 * MB);   // [B,H,S,HD] fp16 (pre-scaled by EC)
  ushort* Kw  = (ushort*)(w + 8 * MB);
  ushort* Vw  = (ushort*)(w + 16 * MB);
  ushort* Cw  = (ushort*)(w + 24 * MB);  // ctx [M,1024] fp16
  ushort* Xh  = (ushort*)(w + 32 * MB);  // x fp16 [M,1024]
  ushort* WT  = (ushort*)(w + 40 * MB);  // 4 x 2 MB fp16 W^T planes
  ushort* Whq = WT + 0 * 1048576;
  ushort* Whk = WT + 1 * 1048576;
  ushort* Whv = WT + 2 * 1048576;
  ushort* Who = WT + 3 * 1048576;

  const dim3 blk(256);

  SplitP sp;
  sp.W[0] = Wq; sp.W[1] = Wk; sp.W[2] = Wv; sp.W[3] = Wo;
  sp.Th[0] = Whq; sp.Th[1] = Whk; sp.Th[2] = Whv; sp.Th[3] = Who;
  prep_kernel<<<dim3(5120), blk, 0, stream>>>(x, Xh, sp);

  GemmP pq;
  pq.Bh[0] = Whq; pq.Bh[1] = Whk; pq.Bh[2] = Whv;
  pq.bias[0] = bq; pq.bias[1] = bk; pq.bias[2] = bv;
  pq.Out[0] = Qw; pq.Out[1] = Kw; pq.Out[2] = Vw;
  gemm_f16<true><<<dim3(Mc / 128, Dc / 128, 3), blk, 0, stream>>>(Xh, pq);

  attn_mfma3<<<dim3(256), blk, 0, stream>>>(Qw, Kw, Vw, Cw);

  GemmP po;
  po.Bh[0] = po.Bh[1] = po.Bh[2] = Who;
  po.bias[0] = po.bias[1] = po.bias[2] = bo;
  po.Out[0] = po.Out[1] = po.Out[2] = d_out;
  gemm_f16<false><<<dim3(Mc / 128, Dc / 128, 1), blk, 0, stream>>>(Cw, po);
}